// Round 1
// baseline (4011.171 us; speedup 1.0000x reference)
//
#include <hip/hip_runtime.h>
#include <hip/hip_bf16.h>

// Problem constants
#define BS    8192
#define DIM   256
#define MROWS 128
#define NCOLS 128
#define KTOT  (MROWS * NCOLS)   // 16384 codebook entries

// ---------------------------------------------------------------------------
// K1: w_sq[k] = sum_d w[k][d]^2.  One wave per row, 4 rows per 256-thread block.
__global__ void wsq_kernel(const float* __restrict__ w, float* __restrict__ wsq) {
    int wid = threadIdx.x >> 6, lane = threadIdx.x & 63;
    int row = blockIdx.x * 4 + wid;
    float4 v = *(const float4*)&w[row * DIM + lane * 4];
    float s = v.x * v.x + v.y * v.y + v.z * v.z + v.w * v.w;
    #pragma unroll
    for (int off = 32; off; off >>= 1) s += __shfl_down(s, off, 64);
    if (lane == 0) wsq[row] = s;
}

// ---------------------------------------------------------------------------
// K2a: init argmin keys to +inf (ws is poisoned 0xAA which is NOT a safe identity)
__global__ void init_keys_kernel(unsigned long long* __restrict__ keys) {
    int i = blockIdx.x * 256 + threadIdx.x;
    keys[i] = ~0ULL;
}

// order-preserving f32 -> u32 map (ascending)
__device__ inline unsigned int fmap(float f) {
    unsigned int b = __float_as_uint(f);
    return (b & 0x80000000u) ? ~b : (b | 0x80000000u);
}

// ---------------------------------------------------------------------------
// K2: BMU. Grid 512 = 128 sample-tiles(64 samples) x 4 k-splits(4096 k each).
// Block 256 threads: trow=tid>>5 (8 sample-groups of 8), tcol=tid&31 (32 k-groups of 8).
// Per k-tile of 256 k: GEMM via 16-dim chunks staged kk-major in LDS; 8x8 micro-tile.
// Score s = wsq[k] - 2*dot; running per-thread min; block reduce; global atomicMin on
// packed (mapped_value<<32 | k)  => ties resolve to smallest k like jnp.argmin.
__global__ __launch_bounds__(256, 2) void bmu_kernel(
    const float* __restrict__ data, const float* __restrict__ w,
    const float* __restrict__ wsq, unsigned long long* __restrict__ keys) {
    __shared__ float Xst[16][64];                 // [kk][sample]  4 KB
    __shared__ float Wt[16][256];                 // [kk][k]      16 KB
    __shared__ unsigned long long red[64][32];    //              16 KB

    int bid    = blockIdx.x;
    int stile  = bid & 127;
    int ksplit = bid >> 7;
    int tid  = threadIdx.x;
    int tcol = tid & 31, trow = tid >> 5;
    int s_base = stile * 64;
    int k_base = ksplit * 4096;

    float bestv[8];
    int   bestk[8];
    #pragma unroll
    for (int i = 0; i < 8; i++) { bestv[i] = 3.4e38f; bestk[i] = 0; }

    for (int kt = 0; kt < 16; ++kt) {
        int ktb = k_base + kt * 256;
        float acc[8][8] = {};
        for (int dc = 0; dc < 16; ++dc) {
            // stage X chunk, transposed to kk-major
            {
                int s = tid & 63, q = tid >> 6;
                float4 v = *(const float4*)&data[(s_base + s) * DIM + dc * 16 + q * 4];
                Xst[q * 4 + 0][s] = v.x; Xst[q * 4 + 1][s] = v.y;
                Xst[q * 4 + 2][s] = v.z; Xst[q * 4 + 3][s] = v.w;
            }
            // stage W chunk, transposed to kk-major
            {
                const float4* wp = (const float4*)&w[(ktb + tid) * DIM + dc * 16];
                #pragma unroll
                for (int q = 0; q < 4; q++) {
                    float4 v = wp[q];
                    Wt[q * 4 + 0][tid] = v.x; Wt[q * 4 + 1][tid] = v.y;
                    Wt[q * 4 + 2][tid] = v.z; Wt[q * 4 + 3][tid] = v.w;
                }
            }
            __syncthreads();
            #pragma unroll
            for (int kk = 0; kk < 16; kk++) {
                float xv[8], wv[8];
                *(float4*)&xv[0] = *(const float4*)&Xst[kk][trow * 8];
                *(float4*)&xv[4] = *(const float4*)&Xst[kk][trow * 8 + 4];
                *(float4*)&wv[0] = *(const float4*)&Wt[kk][tcol * 8];
                *(float4*)&wv[4] = *(const float4*)&Wt[kk][tcol * 8 + 4];
                #pragma unroll
                for (int i = 0; i < 8; i++)
                    #pragma unroll
                    for (int j = 0; j < 8; j++)
                        acc[i][j] = fmaf(xv[i], wv[j], acc[i][j]);
            }
            __syncthreads();
        }
        // epilogue: scores + running min (k ascending within thread => stable ties)
        #pragma unroll
        for (int j = 0; j < 8; j++) {
            int k = ktb + tcol * 8 + j;
            float wsv = wsq[k];
            #pragma unroll
            for (int i = 0; i < 8; i++) {
                float sval = fmaf(-2.0f, acc[i][j], wsv);
                if (sval < bestv[i]) { bestv[i] = sval; bestk[i] = k; }
            }
        }
    }
    // pack and block-reduce across the 32 k-columns
    #pragma unroll
    for (int i = 0; i < 8; i++)
        red[trow * 8 + i][tcol] =
            ((unsigned long long)fmap(bestv[i]) << 32) | (unsigned int)bestk[i];
    __syncthreads();
    if (tid < 64) {
        unsigned long long m = red[tid][0];
        #pragma unroll 4
        for (int c = 1; c < 32; c++) {
            unsigned long long v = red[tid][c];
            m = v < m ? v : m;
        }
        atomicMin(&keys[s_base + tid], m);
    }
}

// ---------------------------------------------------------------------------
// K3: px[b][i] = exp(-(i-w0)^2 / (2 sigma^2)), py likewise.  lr cancels; dropped.
__global__ void pxy_kernel(const unsigned long long* __restrict__ keys,
                           const int* __restrict__ it_p,
                           float* __restrict__ px, float* __restrict__ py) {
    int b = blockIdx.x;
    int tid = threadIdx.x;
    unsigned int k = (unsigned int)(keys[b] & 0xFFFFFFFFu);
    int w0 = (int)(k >> 7), w1 = (int)(k & 127);
    float itf = (float)it_p[0];
    const float START_SIGMA = 64.0f;
    const float TAU = (float)(20.0 / 4.1588830833596715);  // 20 / ln(64)
    float sigma = START_SIGMA * expf(-itf / TAU);
    float d2 = 2.0f * sigma * sigma;
    if (tid < 128) {
        float diff = (float)(tid - w0);
        px[b * 128 + tid] = expf(-(diff * diff) / d2);
    } else {
        int j = tid - 128;
        float diff = (float)(j - w1);
        py[b * 128 + j] = expf(-(diff * diff) / d2);
    }
}

// ---------------------------------------------------------------------------
// K4: denom[i][j] = sum_b px[b][i] * py[b][j].  Grid 128 (one i per block), 128 threads.
__global__ void denom_kernel(const float* __restrict__ px, const float* __restrict__ py,
                             float* __restrict__ denom) {
    int i = blockIdx.x, j = threadIdx.x;
    float a0 = 0.f, a1 = 0.f, a2 = 0.f, a3 = 0.f;
    for (int b = 0; b < BS; b += 4) {
        a0 = fmaf(px[(b + 0) * 128 + i], py[(b + 0) * 128 + j], a0);
        a1 = fmaf(px[(b + 1) * 128 + i], py[(b + 1) * 128 + j], a1);
        a2 = fmaf(px[(b + 2) * 128 + i], py[(b + 2) * 128 + j], a2);
        a3 = fmaf(px[(b + 3) * 128 + i], py[(b + 3) * 128 + j], a3);
    }
    denom[i * 128 + j] = (a0 + a1) + (a2 + a3);
}

// ---------------------------------------------------------------------------
// K5: numer[k][d] = sum_b p[b,k]*x[b,d], p folded at staging (p = px*py).
// Grid 256 blocks (k-tile 64 = one half-row i), block 256: jg=tid>>5 (8 j-groups of 8),
// d0=(tid&31)*8 (8 dims each).  8x8 micro-tile, writes straight into d_out.
__global__ __launch_bounds__(256) void numer_kernel(
    const float* __restrict__ data, const float* __restrict__ px,
    const float* __restrict__ py, float* __restrict__ out) {
    __shared__ float Ps[128][64];  // 32 KB
    int ktb = blockIdx.x * 64;
    int i   = ktb >> 7;
    int j0  = ktb & 127;
    int tid = threadIdx.x;
    int jg  = tid >> 5;
    int d0  = (tid & 31) * 8;
    float acc[8][8] = {};  // [jj][dd]

    for (int b0 = 0; b0 < BS; b0 += 128) {
        {   // stage Ps[b][jj] = px[b][i] * py[b][j0+jj]
            int b    = tid >> 1;
            int half = (tid & 1) * 32;
            float pxv = px[(b0 + b) * 128 + i];
            const float4* pyp = (const float4*)&py[(b0 + b) * 128 + j0 + half];
            float4* psp = (float4*)&Ps[b][half];
            #pragma unroll
            for (int q = 0; q < 8; q++) {
                float4 v = pyp[q];
                v.x *= pxv; v.y *= pxv; v.z *= pxv; v.w *= pxv;
                psp[q] = v;
            }
        }
        __syncthreads();
        #pragma unroll 4
        for (int b = 0; b < 128; b++) {
            float xv[8], pv[8];
            *(float4*)&xv[0] = *(const float4*)&data[(b0 + b) * DIM + d0];
            *(float4*)&xv[4] = *(const float4*)&data[(b0 + b) * DIM + d0 + 4];
            *(float4*)&pv[0] = *(const float4*)&Ps[b][jg * 8];
            *(float4*)&pv[4] = *(const float4*)&Ps[b][jg * 8 + 4];
            #pragma unroll
            for (int jj = 0; jj < 8; jj++)
                #pragma unroll
                for (int dd = 0; dd < 8; dd++)
                    acc[jj][dd] = fmaf(pv[jj], xv[dd], acc[jj][dd]);
        }
        __syncthreads();
    }
    #pragma unroll
    for (int jj = 0; jj < 8; jj++) {
        int k = ktb + jg * 8 + jj;
        *(float4*)&out[k * DIM + d0]     = *(float4*)&acc[jj][0];
        *(float4*)&out[k * DIM + d0 + 4] = *(float4*)&acc[jj][4];
    }
}

// ---------------------------------------------------------------------------
// K6: out[k][d] = denom[k]!=0 ? out[k][d]/denom[k] : w[k][d]
__global__ void finalize_kernel(float* __restrict__ out, const float* __restrict__ denom,
                                const float* __restrict__ w) {
    int idx = blockIdx.x * 256 + threadIdx.x;
    int e = idx * 4;
    int k = e >> 8;  // /DIM
    float dv = denom[k];
    float4 nv = *(float4*)&out[e];
    float4 wv = *(const float4*)&w[e];
    float4 r;
    if (dv != 0.0f) {
        r.x = nv.x / dv; r.y = nv.y / dv; r.z = nv.z / dv; r.w = nv.w / dv;
    } else {
        r = wv;
    }
    *(float4*)&out[e] = r;
}

// ---------------------------------------------------------------------------
extern "C" void kernel_launch(void* const* d_in, const int* in_sizes, int n_in,
                              void* d_out, int out_size, void* d_ws, size_t ws_size,
                              hipStream_t stream) {
    const float* data = (const float*)d_in[0];   // [8192, 256] f32
    const float* w    = (const float*)d_in[1];   // [128,128,256] f32
    const int*   itp  = (const int*)d_in[2];     // scalar
    float* out = (float*)d_out;                  // [128,128,256] f32

    char* ws = (char*)d_ws;
    float*              wsq   = (float*)(ws + 0);                    //  64 KB
    unsigned long long* keys  = (unsigned long long*)(ws + 65536);   //  64 KB
    float*              px    = (float*)(ws + 131072);               //   4 MB
    float*              py    = (float*)(ws + 131072 + 4194304);     //   4 MB
    float*              denom = (float*)(ws + 131072 + 8388608);     //  64 KB

    wsq_kernel<<<KTOT / 4, 256, 0, stream>>>(w, wsq);
    init_keys_kernel<<<BS / 256, 256, 0, stream>>>(keys);
    bmu_kernel<<<512, 256, 0, stream>>>(data, w, wsq, keys);
    pxy_kernel<<<BS, 256, 0, stream>>>(keys, itp, px, py);
    denom_kernel<<<128, 128, 0, stream>>>(px, py, denom);
    numer_kernel<<<256, 256, 0, stream>>>(data, px, py, out);
    finalize_kernel<<<KTOT * DIM / 4 / 256, 256, 0, stream>>>(out, denom, w);
}

// Round 2
// 1447.066 us; speedup vs baseline: 2.7719x; 2.7719x over previous
//
#include <hip/hip_runtime.h>
#include <hip/hip_bf16.h>

// Problem constants
#define BS    8192
#define DIM   256
#define MROWS 128
#define NCOLS 128
#define KTOT  (MROWS * NCOLS)   // 16384 codebook entries

typedef __attribute__((ext_vector_type(8))) short short8;
typedef __attribute__((ext_vector_type(4))) float f32x4;

// f32 -> bf16 round-to-nearest-even (bit trick; no NaN inputs here)
__device__ inline ushort f2bf(float f) {
    unsigned int x = __float_as_uint(f);
    return (ushort)((x + 0x7FFFu + ((x >> 16) & 1u)) >> 16);
}

// async global->LDS, 16B per lane; lds dest = wave-uniform base + lane*16
__device__ inline void gload_lds16(const void* g, void* l) {
    __builtin_amdgcn_global_load_lds(
        (const __attribute__((address_space(1))) unsigned int*)g,
        (__attribute__((address_space(3))) unsigned int*)l, 16, 0, 0);
}

// ---------------------------------------------------------------------------
// K1: w_sq[k] = sum_d w[k][d]^2.
__global__ void wsq_kernel(const float* __restrict__ w, float* __restrict__ wsq) {
    int wid = threadIdx.x >> 6, lane = threadIdx.x & 63;
    int row = blockIdx.x * 4 + wid;
    float4 v = *(const float4*)&w[row * DIM + lane * 4];
    float s = v.x * v.x + v.y * v.y + v.z * v.z + v.w * v.w;
    #pragma unroll
    for (int off = 32; off; off >>= 1) s += __shfl_down(s, off, 64);
    if (lane == 0) wsq[row] = s;
}

// ---------------------------------------------------------------------------
__global__ void init_keys_kernel(unsigned long long* __restrict__ keys) {
    int i = blockIdx.x * 256 + threadIdx.x;
    keys[i] = ~0ULL;
}

__global__ void zero_out_kernel(float* __restrict__ p) {
    int idx = blockIdx.x * 256 + threadIdx.x;
    *(float4*)&p[idx * 4] = make_float4(0.f, 0.f, 0.f, 0.f);
}

// order-preserving f32 -> u32 map (ascending)
__device__ inline unsigned int fmap(float f) {
    unsigned int b = __float_as_uint(f);
    return (b & 0x80000000u) ? ~b : (b | 0x80000000u);
}

// ---------------------------------------------------------------------------
// K2: BMU (f32 VALU, unchanged from round 1 — exact argmin matters here).
__global__ __launch_bounds__(256, 2) void bmu_kernel(
    const float* __restrict__ data, const float* __restrict__ w,
    const float* __restrict__ wsq, unsigned long long* __restrict__ keys) {
    __shared__ float Xst[16][64];
    __shared__ float Wt[16][256];
    __shared__ unsigned long long red[64][32];

    int bid    = blockIdx.x;
    int stile  = bid & 127;
    int ksplit = bid >> 7;
    int tid  = threadIdx.x;
    int tcol = tid & 31, trow = tid >> 5;
    int s_base = stile * 64;
    int k_base = ksplit * 4096;

    float bestv[8];
    int   bestk[8];
    #pragma unroll
    for (int i = 0; i < 8; i++) { bestv[i] = 3.4e38f; bestk[i] = 0; }

    for (int kt = 0; kt < 16; ++kt) {
        int ktb = k_base + kt * 256;
        float acc[8][8] = {};
        for (int dc = 0; dc < 16; ++dc) {
            {
                int s = tid & 63, q = tid >> 6;
                float4 v = *(const float4*)&data[(s_base + s) * DIM + dc * 16 + q * 4];
                Xst[q * 4 + 0][s] = v.x; Xst[q * 4 + 1][s] = v.y;
                Xst[q * 4 + 2][s] = v.z; Xst[q * 4 + 3][s] = v.w;
            }
            {
                const float4* wp = (const float4*)&w[(size_t)(ktb + tid) * DIM + dc * 16];
                #pragma unroll
                for (int q = 0; q < 4; q++) {
                    float4 v = wp[q];
                    Wt[q * 4 + 0][tid] = v.x; Wt[q * 4 + 1][tid] = v.y;
                    Wt[q * 4 + 2][tid] = v.z; Wt[q * 4 + 3][tid] = v.w;
                }
            }
            __syncthreads();
            #pragma unroll
            for (int kk = 0; kk < 16; kk++) {
                float xv[8], wv[8];
                *(float4*)&xv[0] = *(const float4*)&Xst[kk][trow * 8];
                *(float4*)&xv[4] = *(const float4*)&Xst[kk][trow * 8 + 4];
                *(float4*)&wv[0] = *(const float4*)&Wt[kk][tcol * 8];
                *(float4*)&wv[4] = *(const float4*)&Wt[kk][tcol * 8 + 4];
                #pragma unroll
                for (int i = 0; i < 8; i++)
                    #pragma unroll
                    for (int j = 0; j < 8; j++)
                        acc[i][j] = fmaf(xv[i], wv[j], acc[i][j]);
            }
            __syncthreads();
        }
        #pragma unroll
        for (int j = 0; j < 8; j++) {
            int k = ktb + tcol * 8 + j;
            float wsv = wsq[k];
            #pragma unroll
            for (int i = 0; i < 8; i++) {
                float sval = fmaf(-2.0f, acc[i][j], wsv);
                if (sval < bestv[i]) { bestv[i] = sval; bestk[i] = k; }
            }
        }
    }
    #pragma unroll
    for (int i = 0; i < 8; i++)
        red[trow * 8 + i][tcol] =
            ((unsigned long long)fmap(bestv[i]) << 32) | (unsigned int)bestk[i];
    __syncthreads();
    if (tid < 64) {
        unsigned long long m = red[tid][0];
        #pragma unroll 4
        for (int c = 1; c < 32; c++) {
            unsigned long long v = red[tid][c];
            m = v < m ? v : m;
        }
        atomicMin(&keys[s_base + tid], m);
    }
}

// ---------------------------------------------------------------------------
// K3: px/py Gaussian tables (lr cancels in numer/denom; dropped).
__global__ void pxy_kernel(const unsigned long long* __restrict__ keys,
                           const int* __restrict__ it_p,
                           float* __restrict__ px, float* __restrict__ py) {
    int b = blockIdx.x;
    int tid = threadIdx.x;
    unsigned int k = (unsigned int)(keys[b] & 0xFFFFFFFFu);
    int w0 = (int)(k >> 7), w1 = (int)(k & 127);
    float itf = (float)it_p[0];
    const float START_SIGMA = 64.0f;
    const float TAU = (float)(20.0 / 4.1588830833596715);  // 20 / ln(64)
    float sigma = START_SIGMA * expf(-itf / TAU);
    float d2 = 2.0f * sigma * sigma;
    if (tid < 128) {
        float diff = (float)(tid - w0);
        px[b * 128 + tid] = expf(-(diff * diff) / d2);
    } else {
        int j = tid - 128;
        float diff = (float)(j - w1);
        py[b * 128 + j] = expf(-(diff * diff) / d2);
    }
}

// ---------------------------------------------------------------------------
// Transpose f32 [rows][cols] -> [cols][rows], 64x64 tiles.
__global__ void tpose_f32_kernel(const float* __restrict__ in, float* __restrict__ outT,
                                 int rows, int cols) {
    __shared__ float tile[64][68];
    int b0 = blockIdx.x * 64;
    int c0 = blockIdx.y * 64;
    int t = threadIdx.x;
    int rr = t >> 4, seg = t & 15;
    #pragma unroll
    for (int p = 0; p < 4; ++p) {
        int row = rr + p * 16;
        float4 v = *(const float4*)&in[(size_t)(b0 + row) * cols + c0 + seg * 4];
        tile[seg * 4 + 0][row] = v.x; tile[seg * 4 + 1][row] = v.y;
        tile[seg * 4 + 2][row] = v.z; tile[seg * 4 + 3][row] = v.w;
    }
    __syncthreads();
    #pragma unroll
    for (int p = 0; p < 4; ++p) {
        int crow = rr + p * 16;
        *(float4*)&outT[(size_t)(c0 + crow) * rows + b0 + seg * 4] =
            *(float4*)&tile[crow][seg * 4];
    }
}

// Transpose + f32->bf16: data [8192][256] -> xT [256][8192] (ushort).
__global__ void tpose_cvt_bf16_kernel(const float* __restrict__ in, ushort* __restrict__ outT) {
    __shared__ float tile[64][68];
    int b0 = blockIdx.x * 64;
    int d0 = blockIdx.y * 64;
    int t = threadIdx.x;
    int rr = t >> 4, seg = t & 15;
    #pragma unroll
    for (int p = 0; p < 4; ++p) {
        int row = rr + p * 16;
        float4 v = *(const float4*)&in[(size_t)(b0 + row) * DIM + d0 + seg * 4];
        tile[seg * 4 + 0][row] = v.x; tile[seg * 4 + 1][row] = v.y;
        tile[seg * 4 + 2][row] = v.z; tile[seg * 4 + 3][row] = v.w;
    }
    __syncthreads();
    #pragma unroll
    for (int p = 0; p < 4; ++p) {
        int drow = rr + p * 16;
        float4 v = *(float4*)&tile[drow][seg * 4];
        ushort4 u;
        u.x = f2bf(v.x); u.y = f2bf(v.y); u.z = f2bf(v.z); u.w = f2bf(v.w);
        *(ushort4*)&outT[(size_t)(d0 + drow) * BS + b0 + seg * 4] = u;
    }
}

// ---------------------------------------------------------------------------
// K4: denom[i][j] = sum_b px[b][i]*py[b][j]  (f32, unchanged; small)
__global__ void denom_kernel(const float* __restrict__ px, const float* __restrict__ py,
                             float* __restrict__ denom) {
    int i = blockIdx.x, j = threadIdx.x;
    float a0 = 0.f, a1 = 0.f, a2 = 0.f, a3 = 0.f;
    for (int b = 0; b < BS; b += 4) {
        a0 = fmaf(px[(b + 0) * 128 + i], py[(b + 0) * 128 + j], a0);
        a1 = fmaf(px[(b + 1) * 128 + i], py[(b + 1) * 128 + j], a1);
        a2 = fmaf(px[(b + 2) * 128 + i], py[(b + 2) * 128 + j], a2);
        a3 = fmaf(px[(b + 3) * 128 + i], py[(b + 3) * 128 + j], a3);
    }
    denom[i * 128 + j] = (a0 + a1) + (a2 + a3);
}

// ---------------------------------------------------------------------------
// K5: numer = P^T X via bf16 MFMA 16x16x32 (m97 structure).
// Grid (128 i, 2 d-tiles, 4 K-splits) = 1024 blocks.  Tile: M=128 (j), N=128 (d), K=2048.
// A[j][b] = pyT[j][b]*pxT[i][b] computed at staging (ds_write_b128, lane-contiguous).
// B[d][b] = xT (bf16, K-contiguous) staged via global_load_lds width-16.
// Partial tiles atomicAdd'ed into zero-initialized out.
__global__ __launch_bounds__(256) void numer_mfma_kernel(
    const float* __restrict__ pxT, const float* __restrict__ pyT,
    const ushort* __restrict__ xT, float* __restrict__ out) {
    __shared__ ushort Alds[128 * 32];  // [j][b] rows of 64B
    __shared__ ushort Blds[128 * 32];  // [d][b] rows of 64B

    int i   = blockIdx.x;
    int d0  = blockIdx.y * 128;
    int ks  = blockIdx.z;
    int tid = threadIdx.x;
    int w = tid >> 6, lane = tid & 63;
    int wm = (w & 1) * 64, wn = (w >> 1) * 64;
    int lm = lane & 15, quad = lane >> 4;

    f32x4 acc[4][4];
    #pragma unroll
    for (int mi = 0; mi < 4; ++mi)
        #pragma unroll
        for (int ni = 0; ni < 4; ++ni)
            acc[mi][ni] = (f32x4){0.f, 0.f, 0.f, 0.f};

    const float* pxrow = pxT + (size_t)i * BS;
    int aj0 = tid >> 2;            // A row (phase 0); +64 for phase 1
    int ab  = (tid & 3) * 8;       // A b-offset (8 bf16 = 16B)
    int brl = w * 32 + (lane >> 2);  // B row (issue 0); +16 for issue 1
    int bcl = (lane & 3) * 8;

    for (int kb = ks * 2048; kb < ks * 2048 + 2048; kb += 32) {
        // B-tile: 128 rows x 32 b of bf16 = 8 KB, 2 wave-issues per wave
        gload_lds16(xT + (size_t)(d0 + brl) * BS + kb + bcl,
                    &Blds[(w * 32) * 32]);
        gload_lds16(xT + (size_t)(d0 + brl + 16) * BS + kb + bcl,
                    &Blds[(w * 32 + 16) * 32]);
        // A-tile: compute p = py*px, cvt bf16, lane-contiguous ds_write_b128
        #pragma unroll
        for (int ph = 0; ph < 2; ++ph) {
            int j = aj0 + ph * 64;
            const float* pyr = pyT + (size_t)j * BS + kb + ab;
            float4 y0 = *(const float4*)pyr;
            float4 y1 = *(const float4*)(pyr + 4);
            float4 x0 = *(const float4*)&pxrow[kb + ab];
            float4 x1 = *(const float4*)&pxrow[kb + ab + 4];
            union { ushort u[8]; float4 v; } pk;
            pk.u[0] = f2bf(y0.x * x0.x); pk.u[1] = f2bf(y0.y * x0.y);
            pk.u[2] = f2bf(y0.z * x0.z); pk.u[3] = f2bf(y0.w * x0.w);
            pk.u[4] = f2bf(y1.x * x1.x); pk.u[5] = f2bf(y1.y * x1.y);
            pk.u[6] = f2bf(y1.z * x1.z); pk.u[7] = f2bf(y1.w * x1.w);
            *(float4*)&Alds[j * 32 + ab] = pk.v;
        }
        __syncthreads();
        short8 af[4], bg[4];
        #pragma unroll
        for (int mi = 0; mi < 4; ++mi)
            af[mi] = *(const short8*)&Alds[(wm + mi * 16 + lm) * 32 + quad * 8];
        #pragma unroll
        for (int ni = 0; ni < 4; ++ni)
            bg[ni] = *(const short8*)&Blds[(wn + ni * 16 + lm) * 32 + quad * 8];
        #pragma unroll
        for (int mi = 0; mi < 4; ++mi)
            #pragma unroll
            for (int ni = 0; ni < 4; ++ni)
                acc[mi][ni] = __builtin_amdgcn_mfma_f32_16x16x32_bf16(
                    af[mi], bg[ni], acc[mi][ni], 0, 0, 0);
        __syncthreads();
    }
    // epilogue: C row=(quad*4+reg), col=lm  -> atomicAdd partials
    #pragma unroll
    for (int mi = 0; mi < 4; ++mi) {
        int j = i * 128 + wm + mi * 16 + quad * 4;
        #pragma unroll
        for (int ni = 0; ni < 4; ++ni) {
            int d = d0 + wn + ni * 16 + lm;
            float* op = &out[(size_t)j * DIM + d];
            atomicAdd(op + 0 * DIM, acc[mi][ni][0]);
            atomicAdd(op + 1 * DIM, acc[mi][ni][1]);
            atomicAdd(op + 2 * DIM, acc[mi][ni][2]);
            atomicAdd(op + 3 * DIM, acc[mi][ni][3]);
        }
    }
}

// ---------------------------------------------------------------------------
// K6: out[k][d] = denom[k]!=0 ? out[k][d]/denom[k] : w[k][d]
__global__ void finalize_kernel(float* __restrict__ out, const float* __restrict__ denom,
                                const float* __restrict__ w) {
    int idx = blockIdx.x * 256 + threadIdx.x;
    int e = idx * 4;
    int k = e >> 8;
    float dv = denom[k];
    float4 nv = *(float4*)&out[e];
    float4 wv = *(const float4*)&w[e];
    float4 r;
    if (dv != 0.0f) {
        r.x = nv.x / dv; r.y = nv.y / dv; r.z = nv.z / dv; r.w = nv.w / dv;
    } else {
        r = wv;
    }
    *(float4*)&out[e] = r;
}

// ---------------------------------------------------------------------------
extern "C" void kernel_launch(void* const* d_in, const int* in_sizes, int n_in,
                              void* d_out, int out_size, void* d_ws, size_t ws_size,
                              hipStream_t stream) {
    const float* data = (const float*)d_in[0];   // [8192, 256] f32
    const float* w    = (const float*)d_in[1];   // [128,128,256] f32
    const int*   itp  = (const int*)d_in[2];     // scalar
    float* out = (float*)d_out;                  // [128,128,256] f32

    char* ws = (char*)d_ws;
    float*              wsq   = (float*)(ws + 0);                     //  64 KB
    unsigned long long* keys  = (unsigned long long*)(ws + 65536);    //  64 KB
    float*              px    = (float*)(ws + 131072);                //   4 MB [b][i]
    float*              py    = (float*)(ws + 4325376);               //   4 MB [b][j]
    float*              denom = (float*)(ws + 8519680);               //  64 KB
    float*              pxT   = (float*)(ws + 8585216);               //   4 MB [i][b]
    float*              pyT   = (float*)(ws + 12779520);              //   4 MB [j][b]
    ushort*             xT    = (ushort*)(ws + 16973824);             //   4 MB [d][b] bf16

    zero_out_kernel<<<KTOT * DIM / 1024, 256, 0, stream>>>(out);
    tpose_cvt_bf16_kernel<<<dim3(BS / 64, DIM / 64), 256, 0, stream>>>(data, xT);
    wsq_kernel<<<KTOT / 4, 256, 0, stream>>>(w, wsq);
    init_keys_kernel<<<BS / 256, 256, 0, stream>>>(keys);
    bmu_kernel<<<512, 256, 0, stream>>>(data, w, wsq, keys);
    pxy_kernel<<<BS, 256, 0, stream>>>(keys, itp, px, py);
    tpose_f32_kernel<<<dim3(BS / 64, 2), 256, 0, stream>>>(px, pxT, BS, 128);
    tpose_f32_kernel<<<dim3(BS / 64, 2), 256, 0, stream>>>(py, pyT, BS, 128);
    denom_kernel<<<128, 128, 0, stream>>>(px, py, denom);
    numer_mfma_kernel<<<dim3(128, 2, 4), 256, 0, stream>>>(pxT, pyT, xT, out);
    finalize_kernel<<<KTOT * DIM / 1024, 256, 0, stream>>>(out, denom, w);
}

// Round 3
// 791.160 us; speedup vs baseline: 5.0700x; 1.8290x over previous
//
#include <hip/hip_runtime.h>
#include <hip/hip_bf16.h>

// Problem constants
#define BS    8192
#define DIM   256
#define MROWS 128
#define NCOLS 128
#define KTOT  (MROWS * NCOLS)   // 16384 codebook entries

typedef __attribute__((ext_vector_type(8))) short short8;
typedef __attribute__((ext_vector_type(4))) float f32x4;
typedef unsigned long long u64;

// f32 -> bf16 round-to-nearest-even (bit trick; inputs finite)
__device__ inline ushort f2bf(float f) {
    unsigned int x = __float_as_uint(f);
    return (ushort)((x + 0x7FFFu + ((x >> 16) & 1u)) >> 16);
}
__device__ inline float bf2f(ushort h) {
    return __uint_as_float((unsigned int)h << 16);
}

// async global->LDS, 16B per lane; lds dest = wave-uniform base + lane*16
__device__ inline void gload_lds16(const void* g, void* l) {
    __builtin_amdgcn_global_load_lds(
        (const __attribute__((address_space(1))) unsigned int*)g,
        (__attribute__((address_space(3))) unsigned int*)l, 16, 0, 0);
}

// order-preserving f32 -> u32 map (ascending)
__device__ inline unsigned int fmap(float f) {
    unsigned int b = __float_as_uint(f);
    return (b & 0x80000000u) ? ~b : (b | 0x80000000u);
}

// ---------------------------------------------------------------------------
// Split w into bf16 hi/lo + compute wsq, one wave per row (4 rows/block).
__global__ void wsplit_kernel(const float* __restrict__ w, ushort* __restrict__ wh,
                              ushort* __restrict__ wl, float* __restrict__ wsq) {
    int wid = threadIdx.x >> 6, lane = threadIdx.x & 63;
    size_t row = blockIdx.x * 4 + wid;
    float4 v = *(const float4*)&w[row * DIM + lane * 4];
    ushort4 h, l;
    h.x = f2bf(v.x); h.y = f2bf(v.y); h.z = f2bf(v.z); h.w = f2bf(v.w);
    l.x = f2bf(v.x - bf2f(h.x)); l.y = f2bf(v.y - bf2f(h.y));
    l.z = f2bf(v.z - bf2f(h.z)); l.w = f2bf(v.w - bf2f(h.w));
    *(ushort4*)&wh[row * DIM + lane * 4] = h;
    *(ushort4*)&wl[row * DIM + lane * 4] = l;
    float s = v.x * v.x + v.y * v.y + v.z * v.z + v.w * v.w;
    #pragma unroll
    for (int off = 32; off; off >>= 1) s += __shfl_down(s, off, 64);
    if (lane == 0) wsq[row] = s;
}

// Split data into bf16 hi/lo.
__global__ void xsplit_kernel(const float* __restrict__ x, ushort* __restrict__ xh,
                              ushort* __restrict__ xl) {
    int idx = blockIdx.x * 256 + threadIdx.x;
    float4 v = *(const float4*)&x[(size_t)idx * 4];
    ushort4 h, l;
    h.x = f2bf(v.x); h.y = f2bf(v.y); h.z = f2bf(v.z); h.w = f2bf(v.w);
    l.x = f2bf(v.x - bf2f(h.x)); l.y = f2bf(v.y - bf2f(h.y));
    l.z = f2bf(v.z - bf2f(h.z)); l.w = f2bf(v.w - bf2f(h.w));
    *(ushort4*)&xh[(size_t)idx * 4] = h;
    *(ushort4*)&xl[(size_t)idx * 4] = l;
}

// ---------------------------------------------------------------------------
__global__ void init_keys_kernel(u64* __restrict__ keys) {
    int i = blockIdx.x * 256 + threadIdx.x;
    keys[i] = ~0ULL;
}

__global__ void zero_out_kernel(float* __restrict__ p) {
    int idx = blockIdx.x * 256 + threadIdx.x;
    *(float4*)&p[idx * 4] = make_float4(0.f, 0.f, 0.f, 0.f);
}

// ---------------------------------------------------------------------------
// BMU via split-bf16 MFMA: dot = xh*wh + xh*wl + xl*wh (err ~2e-4 << min-gap).
// Grid (64 m-tiles, 128 n-tiles). Tile 128 samples x 128 k, BK=32, m97 staging.
// Epilogue: score = wsq[k] - 2*dot; packed-u64 argmin (ties -> lowest k) via
// quad-group shfl_xor + 2-wave LDS combine + global atomicMin.
__global__ __launch_bounds__(256) void bmu_mfma_kernel(
    const ushort* __restrict__ xh, const ushort* __restrict__ xl,
    const ushort* __restrict__ wh, const ushort* __restrict__ wl,
    const float* __restrict__ wsq, u64* __restrict__ keys) {
    __shared__ ushort Ah[128 * 32], Al[128 * 32];   // 16 KB
    __shared__ ushort Bh[128 * 32], Bl[128 * 32];   // 16 KB
    __shared__ u64 red[128][2];                     //  2 KB

    int m0 = blockIdx.x * 128;
    int k0 = blockIdx.y * 128;
    int tid = threadIdx.x, w = tid >> 6, lane = tid & 63;
    int wm = (w & 1) * 64, wn = (w >> 1) * 64;
    int lm = lane & 15, quad = lane >> 4;
    int srow = lane >> 2;          // staging row within 16-row issue
    int scol = (lane & 3) * 8;     // staging elem offset (8 bf16 = 16 B)

    f32x4 acc[4][4];
    #pragma unroll
    for (int mi = 0; mi < 4; ++mi)
        #pragma unroll
        for (int ni = 0; ni < 4; ++ni)
            acc[mi][ni] = (f32x4){0.f, 0.f, 0.f, 0.f};

    for (int kb = 0; kb < DIM; kb += 32) {
        size_t axoff = (size_t)(m0 + w * 32 + srow) * DIM + kb + scol;
        size_t bxoff = (size_t)(k0 + w * 32 + srow) * DIM + kb + scol;
        gload_lds16(xh + axoff,            &Ah[(w * 32) * 32]);
        gload_lds16(xh + axoff + 16 * DIM, &Ah[(w * 32 + 16) * 32]);
        gload_lds16(xl + axoff,            &Al[(w * 32) * 32]);
        gload_lds16(xl + axoff + 16 * DIM, &Al[(w * 32 + 16) * 32]);
        gload_lds16(wh + bxoff,            &Bh[(w * 32) * 32]);
        gload_lds16(wh + bxoff + 16 * DIM, &Bh[(w * 32 + 16) * 32]);
        gload_lds16(wl + bxoff,            &Bl[(w * 32) * 32]);
        gload_lds16(wl + bxoff + 16 * DIM, &Bl[(w * 32 + 16) * 32]);
        __syncthreads();
        short8 bhv[4], blv[4];
        #pragma unroll
        for (int ni = 0; ni < 4; ++ni) {
            bhv[ni] = *(const short8*)&Bh[(wn + ni * 16 + lm) * 32 + quad * 8];
            blv[ni] = *(const short8*)&Bl[(wn + ni * 16 + lm) * 32 + quad * 8];
        }
        #pragma unroll
        for (int mi = 0; mi < 4; ++mi) {
            short8 ahv = *(const short8*)&Ah[(wm + mi * 16 + lm) * 32 + quad * 8];
            short8 alv = *(const short8*)&Al[(wm + mi * 16 + lm) * 32 + quad * 8];
            #pragma unroll
            for (int ni = 0; ni < 4; ++ni) {
                acc[mi][ni] = __builtin_amdgcn_mfma_f32_16x16x32_bf16(
                    ahv, bhv[ni], acc[mi][ni], 0, 0, 0);
                acc[mi][ni] = __builtin_amdgcn_mfma_f32_16x16x32_bf16(
                    ahv, blv[ni], acc[mi][ni], 0, 0, 0);
                acc[mi][ni] = __builtin_amdgcn_mfma_f32_16x16x32_bf16(
                    alv, bhv[ni], acc[mi][ni], 0, 0, 0);
            }
        }
        __syncthreads();
    }

    // epilogue: C row = quad*4+reg, col = lm
    float wsqv[4];
    #pragma unroll
    for (int ni = 0; ni < 4; ++ni) wsqv[ni] = wsq[k0 + wn + ni * 16 + lm];

    #pragma unroll
    for (int mi = 0; mi < 4; ++mi) {
        #pragma unroll
        for (int r = 0; r < 4; ++r) {
            u64 best = ~0ULL;
            #pragma unroll
            for (int ni = 0; ni < 4; ++ni) {
                float sc = fmaf(-2.0f, acc[mi][ni][r], wsqv[ni]);
                u64 p = ((u64)fmap(sc) << 32) |
                        (unsigned int)(k0 + wn + ni * 16 + lm);
                best = p < best ? p : best;
            }
            #pragma unroll
            for (int mask = 1; mask < 16; mask <<= 1) {
                u64 o = __shfl_xor(best, mask, 64);
                best = o < best ? o : best;
            }
            if (lm == 0) red[wm + mi * 16 + quad * 4 + r][w >> 1] = best;
        }
    }
    __syncthreads();
    if (tid < 128) {
        u64 a = red[tid][0], b = red[tid][1];
        atomicMin(&keys[m0 + tid], a < b ? a : b);
    }
}

// ---------------------------------------------------------------------------
// px/py Gaussian tables (lr cancels in numer/denom; dropped).
__global__ void pxy_kernel(const u64* __restrict__ keys,
                           const int* __restrict__ it_p,
                           float* __restrict__ px, float* __restrict__ py) {
    int b = blockIdx.x;
    int tid = threadIdx.x;
    unsigned int k = (unsigned int)(keys[b] & 0xFFFFFFFFu);
    int w0 = (int)(k >> 7), w1 = (int)(k & 127);
    float itf = (float)it_p[0];
    const float START_SIGMA = 64.0f;
    const float TAU = (float)(20.0 / 4.1588830833596715);  // 20 / ln(64)
    float sigma = START_SIGMA * expf(-itf / TAU);
    float d2 = 2.0f * sigma * sigma;
    if (tid < 128) {
        float diff = (float)(tid - w0);
        px[b * 128 + tid] = expf(-(diff * diff) / d2);
    } else {
        int j = tid - 128;
        float diff = (float)(j - w1);
        py[b * 128 + j] = expf(-(diff * diff) / d2);
    }
}

// ---------------------------------------------------------------------------
// Transpose f32 [rows][cols] -> [cols][rows], 64x64 tiles.
__global__ void tpose_f32_kernel(const float* __restrict__ in, float* __restrict__ outT,
                                 int rows, int cols) {
    __shared__ float tile[64][68];
    int b0 = blockIdx.x * 64;
    int c0 = blockIdx.y * 64;
    int t = threadIdx.x;
    int rr = t >> 4, seg = t & 15;
    #pragma unroll
    for (int p = 0; p < 4; ++p) {
        int row = rr + p * 16;
        float4 v = *(const float4*)&in[(size_t)(b0 + row) * cols + c0 + seg * 4];
        tile[seg * 4 + 0][row] = v.x; tile[seg * 4 + 1][row] = v.y;
        tile[seg * 4 + 2][row] = v.z; tile[seg * 4 + 3][row] = v.w;
    }
    __syncthreads();
    #pragma unroll
    for (int p = 0; p < 4; ++p) {
        int crow = rr + p * 16;
        *(float4*)&outT[(size_t)(c0 + crow) * rows + b0 + seg * 4] =
            *(float4*)&tile[crow][seg * 4];
    }
}

// Transpose + f32->bf16: data [8192][256] -> xT [256][8192] (ushort).
__global__ void tpose_cvt_bf16_kernel(const float* __restrict__ in, ushort* __restrict__ outT) {
    __shared__ float tile[64][68];
    int b0 = blockIdx.x * 64;
    int d0 = blockIdx.y * 64;
    int t = threadIdx.x;
    int rr = t >> 4, seg = t & 15;
    #pragma unroll
    for (int p = 0; p < 4; ++p) {
        int row = rr + p * 16;
        float4 v = *(const float4*)&in[(size_t)(b0 + row) * DIM + d0 + seg * 4];
        tile[seg * 4 + 0][row] = v.x; tile[seg * 4 + 1][row] = v.y;
        tile[seg * 4 + 2][row] = v.z; tile[seg * 4 + 3][row] = v.w;
    }
    __syncthreads();
    #pragma unroll
    for (int p = 0; p < 4; ++p) {
        int drow = rr + p * 16;
        float4 v = *(float4*)&tile[drow][seg * 4];
        ushort4 u;
        u.x = f2bf(v.x); u.y = f2bf(v.y); u.z = f2bf(v.z); u.w = f2bf(v.w);
        *(ushort4*)&outT[(size_t)(d0 + drow) * BS + b0 + seg * 4] = u;
    }
}

// ---------------------------------------------------------------------------
// denom[i][j] = sum_b px[b][i]*py[b][j]
__global__ void denom_kernel(const float* __restrict__ px, const float* __restrict__ py,
                             float* __restrict__ denom) {
    int i = blockIdx.x, j = threadIdx.x;
    float a0 = 0.f, a1 = 0.f, a2 = 0.f, a3 = 0.f;
    for (int b = 0; b < BS; b += 4) {
        a0 = fmaf(px[(b + 0) * 128 + i], py[(b + 0) * 128 + j], a0);
        a1 = fmaf(px[(b + 1) * 128 + i], py[(b + 1) * 128 + j], a1);
        a2 = fmaf(px[(b + 2) * 128 + i], py[(b + 2) * 128 + j], a2);
        a3 = fmaf(px[(b + 3) * 128 + i], py[(b + 3) * 128 + j], a3);
    }
    denom[i * 128 + j] = (a0 + a1) + (a2 + a3);
}

// ---------------------------------------------------------------------------
// numer = P^T X via bf16 MFMA (grid 128 i x 2 d-tiles x 4 K-splits, atomicAdd).
__global__ __launch_bounds__(256) void numer_mfma_kernel(
    const float* __restrict__ pxT, const float* __restrict__ pyT,
    const ushort* __restrict__ xT, float* __restrict__ out) {
    __shared__ ushort Alds[128 * 32];
    __shared__ ushort Blds[128 * 32];

    int i   = blockIdx.x;
    int d0  = blockIdx.y * 128;
    int ks  = blockIdx.z;
    int tid = threadIdx.x;
    int w = tid >> 6, lane = tid & 63;
    int wm = (w & 1) * 64, wn = (w >> 1) * 64;
    int lm = lane & 15, quad = lane >> 4;

    f32x4 acc[4][4];
    #pragma unroll
    for (int mi = 0; mi < 4; ++mi)
        #pragma unroll
        for (int ni = 0; ni < 4; ++ni)
            acc[mi][ni] = (f32x4){0.f, 0.f, 0.f, 0.f};

    const float* pxrow = pxT + (size_t)i * BS;
    int aj0 = tid >> 2;
    int ab  = (tid & 3) * 8;
    int brl = w * 32 + (lane >> 2);
    int bcl = (lane & 3) * 8;

    for (int kb = ks * 2048; kb < ks * 2048 + 2048; kb += 32) {
        gload_lds16(xT + (size_t)(d0 + brl) * BS + kb + bcl,
                    &Blds[(w * 32) * 32]);
        gload_lds16(xT + (size_t)(d0 + brl + 16) * BS + kb + bcl,
                    &Blds[(w * 32 + 16) * 32]);
        #pragma unroll
        for (int ph = 0; ph < 2; ++ph) {
            int j = aj0 + ph * 64;
            const float* pyr = pyT + (size_t)j * BS + kb + ab;
            float4 y0 = *(const float4*)pyr;
            float4 y1 = *(const float4*)(pyr + 4);
            float4 x0 = *(const float4*)&pxrow[kb + ab];
            float4 x1 = *(const float4*)&pxrow[kb + ab + 4];
            union { ushort u[8]; float4 v; } pk;
            pk.u[0] = f2bf(y0.x * x0.x); pk.u[1] = f2bf(y0.y * x0.y);
            pk.u[2] = f2bf(y0.z * x0.z); pk.u[3] = f2bf(y0.w * x0.w);
            pk.u[4] = f2bf(y1.x * x1.x); pk.u[5] = f2bf(y1.y * x1.y);
            pk.u[6] = f2bf(y1.z * x1.z); pk.u[7] = f2bf(y1.w * x1.w);
            *(float4*)&Alds[j * 32 + ab] = pk.v;
        }
        __syncthreads();
        short8 af[4], bg[4];
        #pragma unroll
        for (int mi = 0; mi < 4; ++mi)
            af[mi] = *(const short8*)&Alds[(wm + mi * 16 + lm) * 32 + quad * 8];
        #pragma unroll
        for (int ni = 0; ni < 4; ++ni)
            bg[ni] = *(const short8*)&Blds[(wn + ni * 16 + lm) * 32 + quad * 8];
        #pragma unroll
        for (int mi = 0; mi < 4; ++mi)
            #pragma unroll
            for (int ni = 0; ni < 4; ++ni)
                acc[mi][ni] = __builtin_amdgcn_mfma_f32_16x16x32_bf16(
                    af[mi], bg[ni], acc[mi][ni], 0, 0, 0);
        __syncthreads();
    }
    #pragma unroll
    for (int mi = 0; mi < 4; ++mi) {
        int j = i * 128 + wm + mi * 16 + quad * 4;
        #pragma unroll
        for (int ni = 0; ni < 4; ++ni) {
            int d = d0 + wn + ni * 16 + lm;
            float* op = &out[(size_t)j * DIM + d];
            atomicAdd(op + 0 * DIM, acc[mi][ni][0]);
            atomicAdd(op + 1 * DIM, acc[mi][ni][1]);
            atomicAdd(op + 2 * DIM, acc[mi][ni][2]);
            atomicAdd(op + 3 * DIM, acc[mi][ni][3]);
        }
    }
}

// ---------------------------------------------------------------------------
// finalize: out = denom!=0 ? out/denom : w
__global__ void finalize_kernel(float* __restrict__ out, const float* __restrict__ denom,
                                const float* __restrict__ w) {
    int idx = blockIdx.x * 256 + threadIdx.x;
    int e = idx * 4;
    int k = e >> 8;
    float dv = denom[k];
    float4 nv = *(float4*)&out[e];
    float4 wv = *(const float4*)&w[e];
    float4 r;
    if (dv != 0.0f) {
        r.x = nv.x / dv; r.y = nv.y / dv; r.z = nv.z / dv; r.w = nv.w / dv;
    } else {
        r = wv;
    }
    *(float4*)&out[e] = r;
}

// ---------------------------------------------------------------------------
extern "C" void kernel_launch(void* const* d_in, const int* in_sizes, int n_in,
                              void* d_out, int out_size, void* d_ws, size_t ws_size,
                              hipStream_t stream) {
    const float* data = (const float*)d_in[0];   // [8192, 256] f32
    const float* w    = (const float*)d_in[1];   // [128,128,256] f32
    const int*   itp  = (const int*)d_in[2];     // scalar
    float* out = (float*)d_out;                  // [128,128,256] f32

    char* ws = (char*)d_ws;
    size_t off = 0;
    float*  wsq   = (float*)(ws + off);  off += 65536;        //  64 KB
    u64*    keys  = (u64*)(ws + off);    off += 65536;        //  64 KB
    float*  px    = (float*)(ws + off);  off += 4194304;      //   4 MB [b][i]
    float*  py    = (float*)(ws + off);  off += 4194304;      //   4 MB [b][j]
    float*  denom = (float*)(ws + off);  off += 65536;        //  64 KB
    float*  pxT   = (float*)(ws + off);  off += 4194304;      //   4 MB [i][b]
    float*  pyT   = (float*)(ws + off);  off += 4194304;      //   4 MB [j][b]
    ushort* xT    = (ushort*)(ws + off); off += 4194304;      //   4 MB [d][b] bf16
    ushort* xh    = (ushort*)(ws + off); off += 4194304;      //   4 MB [b][d] bf16
    ushort* xl    = (ushort*)(ws + off); off += 4194304;      //   4 MB
    ushort* wh    = (ushort*)(ws + off); off += 8388608;      //   8 MB [k][d] bf16
    ushort* wl    = (ushort*)(ws + off); off += 8388608;      //   8 MB

    zero_out_kernel<<<KTOT * DIM / 1024, 256, 0, stream>>>(out);
    xsplit_kernel<<<BS * DIM / 1024, 256, 0, stream>>>(data, xh, xl);
    wsplit_kernel<<<KTOT / 4, 256, 0, stream>>>(w, wh, wl, wsq);
    tpose_cvt_bf16_kernel<<<dim3(BS / 64, DIM / 64), 256, 0, stream>>>(data, xT);
    init_keys_kernel<<<BS / 256, 256, 0, stream>>>(keys);
    bmu_mfma_kernel<<<dim3(64, 128), 256, 0, stream>>>(xh, xl, wh, wl, wsq, keys);
    pxy_kernel<<<BS, 256, 0, stream>>>(keys, itp, px, py);
    tpose_f32_kernel<<<dim3(BS / 64, 2), 256, 0, stream>>>(px, pxT, BS, 128);
    tpose_f32_kernel<<<dim3(BS / 64, 2), 256, 0, stream>>>(py, pyT, BS, 128);
    denom_kernel<<<128, 128, 0, stream>>>(px, py, denom);
    numer_mfma_kernel<<<dim3(128, 2, 4), 256, 0, stream>>>(pxT, pyT, xT, out);
    finalize_kernel<<<KTOT * DIM / 1024, 256, 0, stream>>>(out, denom, w);
}

// Round 4
// 595.078 us; speedup vs baseline: 6.7406x; 1.3295x over previous
//
#include <hip/hip_runtime.h>
#include <hip/hip_bf16.h>

// Problem constants
#define BS    8192
#define DIM   256
#define MROWS 128
#define NCOLS 128
#define KTOT  (MROWS * NCOLS)   // 16384 codebook entries

typedef __attribute__((ext_vector_type(8))) short short8;
typedef __attribute__((ext_vector_type(4))) float f32x4;
typedef unsigned long long u64;

// f32 -> bf16 round-to-nearest-even (bit trick; inputs finite)
__device__ inline ushort f2bf(float f) {
    unsigned int x = __float_as_uint(f);
    return (ushort)((x + 0x7FFFu + ((x >> 16) & 1u)) >> 16);
}
__device__ inline float bf2f(ushort h) {
    return __uint_as_float((unsigned int)h << 16);
}

// async global->LDS, 16B per lane; lds dest = wave-uniform base + lane*16
__device__ inline void gload_lds16(const void* g, void* l) {
    __builtin_amdgcn_global_load_lds(
        (const __attribute__((address_space(1))) unsigned int*)g,
        (__attribute__((address_space(3))) unsigned int*)l, 16, 0, 0);
}

// order-preserving f32 -> u32 map (ascending)
__device__ inline unsigned int fmap(float f) {
    unsigned int b = __float_as_uint(f);
    return (b & 0x80000000u) ? ~b : (b | 0x80000000u);
}

// ---------------------------------------------------------------------------
// Split w into bf16 hi/lo + compute wsq, one wave per row (4 rows/block).
__global__ void wsplit_kernel(const float* __restrict__ w, ushort* __restrict__ wh,
                              ushort* __restrict__ wl, float* __restrict__ wsq) {
    int wid = threadIdx.x >> 6, lane = threadIdx.x & 63;
    size_t row = blockIdx.x * 4 + wid;
    float4 v = *(const float4*)&w[row * DIM + lane * 4];
    ushort4 h, l;
    h.x = f2bf(v.x); h.y = f2bf(v.y); h.z = f2bf(v.z); h.w = f2bf(v.w);
    l.x = f2bf(v.x - bf2f(h.x)); l.y = f2bf(v.y - bf2f(h.y));
    l.z = f2bf(v.z - bf2f(h.z)); l.w = f2bf(v.w - bf2f(h.w));
    *(ushort4*)&wh[row * DIM + lane * 4] = h;
    *(ushort4*)&wl[row * DIM + lane * 4] = l;
    float s = v.x * v.x + v.y * v.y + v.z * v.z + v.w * v.w;
    #pragma unroll
    for (int off = 32; off; off >>= 1) s += __shfl_down(s, off, 64);
    if (lane == 0) wsq[row] = s;
}

// Split data into bf16 hi/lo.
__global__ void xsplit_kernel(const float* __restrict__ x, ushort* __restrict__ xh,
                              ushort* __restrict__ xl) {
    int idx = blockIdx.x * 256 + threadIdx.x;
    float4 v = *(const float4*)&x[(size_t)idx * 4];
    ushort4 h, l;
    h.x = f2bf(v.x); h.y = f2bf(v.y); h.z = f2bf(v.z); h.w = f2bf(v.w);
    l.x = f2bf(v.x - bf2f(h.x)); l.y = f2bf(v.y - bf2f(h.y));
    l.z = f2bf(v.z - bf2f(h.z)); l.w = f2bf(v.w - bf2f(h.w));
    *(ushort4*)&xh[(size_t)idx * 4] = h;
    *(ushort4*)&xl[(size_t)idx * 4] = l;
}

// ---------------------------------------------------------------------------
__global__ void init_keys_kernel(u64* __restrict__ keys) {
    int i = blockIdx.x * 256 + threadIdx.x;
    keys[i] = ~0ULL;
}

__global__ void zero_out_kernel(float* __restrict__ p) {
    int idx = blockIdx.x * 256 + threadIdx.x;
    *(float4*)&p[idx * 4] = make_float4(0.f, 0.f, 0.f, 0.f);
}

__global__ void zero_denom_kernel(float* __restrict__ p) {
    int idx = blockIdx.x * 256 + threadIdx.x;
    p[idx] = 0.f;
}

// ---------------------------------------------------------------------------
// BMU via split-bf16 MFMA: dot = xh*wh + xh*wl + xl*wh (err ~2e-4 << min-gap).
__global__ __launch_bounds__(256) void bmu_mfma_kernel(
    const ushort* __restrict__ xh, const ushort* __restrict__ xl,
    const ushort* __restrict__ wh, const ushort* __restrict__ wl,
    const float* __restrict__ wsq, u64* __restrict__ keys) {
    __shared__ ushort Ah[128 * 32], Al[128 * 32];   // 16 KB
    __shared__ ushort Bh[128 * 32], Bl[128 * 32];   // 16 KB
    __shared__ u64 red[128][2];                     //  2 KB

    int m0 = blockIdx.x * 128;
    int k0 = blockIdx.y * 128;
    int tid = threadIdx.x, w = tid >> 6, lane = tid & 63;
    int wm = (w & 1) * 64, wn = (w >> 1) * 64;
    int lm = lane & 15, quad = lane >> 4;
    int srow = lane >> 2;          // staging row within 16-row issue
    int scol = (lane & 3) * 8;     // staging elem offset (8 bf16 = 16 B)

    f32x4 acc[4][4];
    #pragma unroll
    for (int mi = 0; mi < 4; ++mi)
        #pragma unroll
        for (int ni = 0; ni < 4; ++ni)
            acc[mi][ni] = (f32x4){0.f, 0.f, 0.f, 0.f};

    for (int kb = 0; kb < DIM; kb += 32) {
        size_t axoff = (size_t)(m0 + w * 32 + srow) * DIM + kb + scol;
        size_t bxoff = (size_t)(k0 + w * 32 + srow) * DIM + kb + scol;
        gload_lds16(xh + axoff,            &Ah[(w * 32) * 32]);
        gload_lds16(xh + axoff + 16 * DIM, &Ah[(w * 32 + 16) * 32]);
        gload_lds16(xl + axoff,            &Al[(w * 32) * 32]);
        gload_lds16(xl + axoff + 16 * DIM, &Al[(w * 32 + 16) * 32]);
        gload_lds16(wh + bxoff,            &Bh[(w * 32) * 32]);
        gload_lds16(wh + bxoff + 16 * DIM, &Bh[(w * 32 + 16) * 32]);
        gload_lds16(wl + bxoff,            &Bl[(w * 32) * 32]);
        gload_lds16(wl + bxoff + 16 * DIM, &Bl[(w * 32 + 16) * 32]);
        __syncthreads();
        short8 bhv[4], blv[4];
        #pragma unroll
        for (int ni = 0; ni < 4; ++ni) {
            bhv[ni] = *(const short8*)&Bh[(wn + ni * 16 + lm) * 32 + quad * 8];
            blv[ni] = *(const short8*)&Bl[(wn + ni * 16 + lm) * 32 + quad * 8];
        }
        #pragma unroll
        for (int mi = 0; mi < 4; ++mi) {
            short8 ahv = *(const short8*)&Ah[(wm + mi * 16 + lm) * 32 + quad * 8];
            short8 alv = *(const short8*)&Al[(wm + mi * 16 + lm) * 32 + quad * 8];
            #pragma unroll
            for (int ni = 0; ni < 4; ++ni) {
                acc[mi][ni] = __builtin_amdgcn_mfma_f32_16x16x32_bf16(
                    ahv, bhv[ni], acc[mi][ni], 0, 0, 0);
                acc[mi][ni] = __builtin_amdgcn_mfma_f32_16x16x32_bf16(
                    ahv, blv[ni], acc[mi][ni], 0, 0, 0);
                acc[mi][ni] = __builtin_amdgcn_mfma_f32_16x16x32_bf16(
                    alv, bhv[ni], acc[mi][ni], 0, 0, 0);
            }
        }
        __syncthreads();
    }

    // epilogue: C row = quad*4+reg, col = lm
    float wsqv[4];
    #pragma unroll
    for (int ni = 0; ni < 4; ++ni) wsqv[ni] = wsq[k0 + wn + ni * 16 + lm];

    #pragma unroll
    for (int mi = 0; mi < 4; ++mi) {
        #pragma unroll
        for (int r = 0; r < 4; ++r) {
            u64 best = ~0ULL;
            #pragma unroll
            for (int ni = 0; ni < 4; ++ni) {
                float sc = fmaf(-2.0f, acc[mi][ni][r], wsqv[ni]);
                u64 p = ((u64)fmap(sc) << 32) |
                        (unsigned int)(k0 + wn + ni * 16 + lm);
                best = p < best ? p : best;
            }
            #pragma unroll
            for (int mask = 1; mask < 16; mask <<= 1) {
                u64 o = __shfl_xor(best, mask, 64);
                best = o < best ? o : best;
            }
            if (lm == 0) red[wm + mi * 16 + quad * 4 + r][w >> 1] = best;
        }
    }
    __syncthreads();
    if (tid < 128) {
        u64 a = red[tid][0], b = red[tid][1];
        atomicMin(&keys[m0 + tid], a < b ? a : b);
    }
}

// ---------------------------------------------------------------------------
// px/py Gaussian tables (lr cancels in numer/denom; dropped).
__global__ void pxy_kernel(const u64* __restrict__ keys,
                           const int* __restrict__ it_p,
                           float* __restrict__ px, float* __restrict__ py) {
    int b = blockIdx.x;
    int tid = threadIdx.x;
    unsigned int k = (unsigned int)(keys[b] & 0xFFFFFFFFu);
    int w0 = (int)(k >> 7), w1 = (int)(k & 127);
    float itf = (float)it_p[0];
    const float START_SIGMA = 64.0f;
    const float TAU = (float)(20.0 / 4.1588830833596715);  // 20 / ln(64)
    float sigma = START_SIGMA * expf(-itf / TAU);
    float d2 = 2.0f * sigma * sigma;
    if (tid < 128) {
        float diff = (float)(tid - w0);
        px[b * 128 + tid] = expf(-(diff * diff) / d2);
    } else {
        int j = tid - 128;
        float diff = (float)(j - w1);
        py[b * 128 + j] = expf(-(diff * diff) / d2);
    }
}

// ---------------------------------------------------------------------------
// Transpose f32 [rows][cols] -> [cols][rows], 64x64 tiles.
__global__ void tpose_f32_kernel(const float* __restrict__ in, float* __restrict__ outT,
                                 int rows, int cols) {
    __shared__ float tile[64][68];
    int b0 = blockIdx.x * 64;
    int c0 = blockIdx.y * 64;
    int t = threadIdx.x;
    int rr = t >> 4, seg = t & 15;
    #pragma unroll
    for (int p = 0; p < 4; ++p) {
        int row = rr + p * 16;
        float4 v = *(const float4*)&in[(size_t)(b0 + row) * cols + c0 + seg * 4];
        tile[seg * 4 + 0][row] = v.x; tile[seg * 4 + 1][row] = v.y;
        tile[seg * 4 + 2][row] = v.z; tile[seg * 4 + 3][row] = v.w;
    }
    __syncthreads();
    #pragma unroll
    for (int p = 0; p < 4; ++p) {
        int crow = rr + p * 16;
        *(float4*)&outT[(size_t)(c0 + crow) * rows + b0 + seg * 4] =
            *(float4*)&tile[crow][seg * 4];
    }
}

// Transpose + f32->bf16: data [8192][256] -> xT [256][8192] (ushort).
__global__ void tpose_cvt_bf16_kernel(const float* __restrict__ in, ushort* __restrict__ outT) {
    __shared__ float tile[64][68];
    int b0 = blockIdx.x * 64;
    int d0 = blockIdx.y * 64;
    int t = threadIdx.x;
    int rr = t >> 4, seg = t & 15;
    #pragma unroll
    for (int p = 0; p < 4; ++p) {
        int row = rr + p * 16;
        float4 v = *(const float4*)&in[(size_t)(b0 + row) * DIM + d0 + seg * 4];
        tile[seg * 4 + 0][row] = v.x; tile[seg * 4 + 1][row] = v.y;
        tile[seg * 4 + 2][row] = v.z; tile[seg * 4 + 3][row] = v.w;
    }
    __syncthreads();
    #pragma unroll
    for (int p = 0; p < 4; ++p) {
        int drow = rr + p * 16;
        float4 v = *(float4*)&tile[drow][seg * 4];
        ushort4 u;
        u.x = f2bf(v.x); u.y = f2bf(v.y); u.z = f2bf(v.z); u.w = f2bf(v.w);
        *(ushort4*)&outT[(size_t)(d0 + drow) * BS + b0 + seg * 4] = u;
    }
}

// ---------------------------------------------------------------------------
// denom[i][j] = sum_b px[b][i]*py[b][j] as block-parallel outer product.
// Grid 128 blocks x 64-batch chunks; 16x16 thread grid, 8x8 register tile;
// px/py chunk staged in LDS (coalesced); atomicAdd into zeroed denom.
__global__ __launch_bounds__(256) void denom_op_kernel(
    const float* __restrict__ px, const float* __restrict__ py,
    float* __restrict__ denom) {
    __shared__ float pxs[64][128];   // 32 KB
    __shared__ float pys[64][128];   // 32 KB
    int b0 = blockIdx.x * 64;
    int tid = threadIdx.x;
    #pragma unroll
    for (int q = 0; q < 8; ++q) {
        int idx = q * 256 + tid;      // float4 units, 0..2047
        int row = idx >> 5;
        int col = (idx & 31) * 4;
        *(float4*)&pxs[row][col] = *(const float4*)&px[(size_t)(b0 + row) * 128 + col];
        *(float4*)&pys[row][col] = *(const float4*)&py[(size_t)(b0 + row) * 128 + col];
    }
    __syncthreads();
    int ig = tid >> 4, jg = tid & 15;
    float acc[8][8] = {};
    for (int b = 0; b < 64; ++b) {
        float pv[8], qv[8];
        *(float4*)&pv[0] = *(float4*)&pxs[b][ig * 8];
        *(float4*)&pv[4] = *(float4*)&pxs[b][ig * 8 + 4];
        *(float4*)&qv[0] = *(float4*)&pys[b][jg * 8];
        *(float4*)&qv[4] = *(float4*)&pys[b][jg * 8 + 4];
        #pragma unroll
        for (int ii = 0; ii < 8; ++ii)
            #pragma unroll
            for (int jj = 0; jj < 8; ++jj)
                acc[ii][jj] = fmaf(pv[ii], qv[jj], acc[ii][jj]);
    }
    #pragma unroll
    for (int ii = 0; ii < 8; ++ii)
        #pragma unroll
        for (int jj = 0; jj < 8; ++jj)
            atomicAdd(&denom[(ig * 8 + ii) * 128 + jg * 8 + jj], acc[ii][jj]);
}

// ---------------------------------------------------------------------------
// numer = P^T X via bf16 MFMA (grid 128 i x 2 d-tiles x 4 K-splits, atomicAdd).
__global__ __launch_bounds__(256) void numer_mfma_kernel(
    const float* __restrict__ pxT, const float* __restrict__ pyT,
    const ushort* __restrict__ xT, float* __restrict__ out) {
    __shared__ ushort Alds[128 * 32];
    __shared__ ushort Blds[128 * 32];

    int i   = blockIdx.x;
    int d0  = blockIdx.y * 128;
    int ks  = blockIdx.z;
    int tid = threadIdx.x;
    int w = tid >> 6, lane = tid & 63;
    int wm = (w & 1) * 64, wn = (w >> 1) * 64;
    int lm = lane & 15, quad = lane >> 4;

    f32x4 acc[4][4];
    #pragma unroll
    for (int mi = 0; mi < 4; ++mi)
        #pragma unroll
        for (int ni = 0; ni < 4; ++ni)
            acc[mi][ni] = (f32x4){0.f, 0.f, 0.f, 0.f};

    const float* pxrow = pxT + (size_t)i * BS;
    int aj0 = tid >> 2;
    int ab  = (tid & 3) * 8;
    int brl = w * 32 + (lane >> 2);
    int bcl = (lane & 3) * 8;

    for (int kb = ks * 2048; kb < ks * 2048 + 2048; kb += 32) {
        gload_lds16(xT + (size_t)(d0 + brl) * BS + kb + bcl,
                    &Blds[(w * 32) * 32]);
        gload_lds16(xT + (size_t)(d0 + brl + 16) * BS + kb + bcl,
                    &Blds[(w * 32 + 16) * 32]);
        #pragma unroll
        for (int ph = 0; ph < 2; ++ph) {
            int j = aj0 + ph * 64;
            const float* pyr = pyT + (size_t)j * BS + kb + ab;
            float4 y0 = *(const float4*)pyr;
            float4 y1 = *(const float4*)(pyr + 4);
            float4 x0 = *(const float4*)&pxrow[kb + ab];
            float4 x1 = *(const float4*)&pxrow[kb + ab + 4];
            union { ushort u[8]; float4 v; } pk;
            pk.u[0] = f2bf(y0.x * x0.x); pk.u[1] = f2bf(y0.y * x0.y);
            pk.u[2] = f2bf(y0.z * x0.z); pk.u[3] = f2bf(y0.w * x0.w);
            pk.u[4] = f2bf(y1.x * x1.x); pk.u[5] = f2bf(y1.y * x1.y);
            pk.u[6] = f2bf(y1.z * x1.z); pk.u[7] = f2bf(y1.w * x1.w);
            *(float4*)&Alds[j * 32 + ab] = pk.v;
        }
        __syncthreads();
        short8 af[4], bg[4];
        #pragma unroll
        for (int mi = 0; mi < 4; ++mi)
            af[mi] = *(const short8*)&Alds[(wm + mi * 16 + lm) * 32 + quad * 8];
        #pragma unroll
        for (int ni = 0; ni < 4; ++ni)
            bg[ni] = *(const short8*)&Blds[(wn + ni * 16 + lm) * 32 + quad * 8];
        #pragma unroll
        for (int mi = 0; mi < 4; ++mi)
            #pragma unroll
            for (int ni = 0; ni < 4; ++ni)
                acc[mi][ni] = __builtin_amdgcn_mfma_f32_16x16x32_bf16(
                    af[mi], bg[ni], acc[mi][ni], 0, 0, 0);
        __syncthreads();
    }
    #pragma unroll
    for (int mi = 0; mi < 4; ++mi) {
        int j = i * 128 + wm + mi * 16 + quad * 4;
        #pragma unroll
        for (int ni = 0; ni < 4; ++ni) {
            int d = d0 + wn + ni * 16 + lm;
            float* op = &out[(size_t)j * DIM + d];
            atomicAdd(op + 0 * DIM, acc[mi][ni][0]);
            atomicAdd(op + 1 * DIM, acc[mi][ni][1]);
            atomicAdd(op + 2 * DIM, acc[mi][ni][2]);
            atomicAdd(op + 3 * DIM, acc[mi][ni][3]);
        }
    }
}

// ---------------------------------------------------------------------------
// finalize: out = denom!=0 ? out/denom : w
__global__ void finalize_kernel(float* __restrict__ out, const float* __restrict__ denom,
                                const float* __restrict__ w) {
    int idx = blockIdx.x * 256 + threadIdx.x;
    int e = idx * 4;
    int k = e >> 8;
    float dv = denom[k];
    float4 nv = *(float4*)&out[e];
    float4 wv = *(const float4*)&w[e];
    float4 r;
    if (dv != 0.0f) {
        r.x = nv.x / dv; r.y = nv.y / dv; r.z = nv.z / dv; r.w = nv.w / dv;
    } else {
        r = wv;
    }
    *(float4*)&out[e] = r;
}

// ---------------------------------------------------------------------------
extern "C" void kernel_launch(void* const* d_in, const int* in_sizes, int n_in,
                              void* d_out, int out_size, void* d_ws, size_t ws_size,
                              hipStream_t stream) {
    const float* data = (const float*)d_in[0];   // [8192, 256] f32
    const float* w    = (const float*)d_in[1];   // [128,128,256] f32
    const int*   itp  = (const int*)d_in[2];     // scalar
    float* out = (float*)d_out;                  // [128,128,256] f32

    char* ws = (char*)d_ws;
    size_t off = 0;
    float*  wsq   = (float*)(ws + off);  off += 65536;        //  64 KB
    u64*    keys  = (u64*)(ws + off);    off += 65536;        //  64 KB
    float*  px    = (float*)(ws + off);  off += 4194304;      //   4 MB [b][i]
    float*  py    = (float*)(ws + off);  off += 4194304;      //   4 MB [b][j]
    float*  denom = (float*)(ws + off);  off += 65536;        //  64 KB
    float*  pxT   = (float*)(ws + off);  off += 4194304;      //   4 MB [i][b]
    float*  pyT   = (float*)(ws + off);  off += 4194304;      //   4 MB [j][b]
    ushort* xT    = (ushort*)(ws + off); off += 4194304;      //   4 MB [d][b] bf16
    ushort* xh    = (ushort*)(ws + off); off += 4194304;      //   4 MB [b][d] bf16
    ushort* xl    = (ushort*)(ws + off); off += 4194304;      //   4 MB
    ushort* wh    = (ushort*)(ws + off); off += 8388608;      //   8 MB [k][d] bf16
    ushort* wl    = (ushort*)(ws + off); off += 8388608;      //   8 MB

    zero_out_kernel<<<KTOT * DIM / 1024, 256, 0, stream>>>(out);
    zero_denom_kernel<<<KTOT / 256, 256, 0, stream>>>(denom);
    xsplit_kernel<<<BS * DIM / 1024, 256, 0, stream>>>(data, xh, xl);
    wsplit_kernel<<<KTOT / 4, 256, 0, stream>>>(w, wh, wl, wsq);
    tpose_cvt_bf16_kernel<<<dim3(BS / 64, DIM / 64), 256, 0, stream>>>(data, xT);
    init_keys_kernel<<<BS / 256, 256, 0, stream>>>(keys);
    bmu_mfma_kernel<<<dim3(64, 128), 256, 0, stream>>>(xh, xl, wh, wl, wsq, keys);
    pxy_kernel<<<BS, 256, 0, stream>>>(keys, itp, px, py);
    tpose_f32_kernel<<<dim3(BS / 64, 2), 256, 0, stream>>>(px, pxT, BS, 128);
    tpose_f32_kernel<<<dim3(BS / 64, 2), 256, 0, stream>>>(py, pyT, BS, 128);
    denom_op_kernel<<<128, 256, 0, stream>>>(px, py, denom);
    numer_mfma_kernel<<<dim3(128, 2, 4), 256, 0, stream>>>(pxT, pyT, xT, out);
    finalize_kernel<<<KTOT * DIM / 1024, 256, 0, stream>>>(out, denom, w);
}